// Round 1
// baseline (101.480 us; speedup 1.0000x reference)
//
#include <hip/hip_runtime.h>
#include <hip/hip_bf16.h>
#include <stdint.h>

// Problem constants
#define M_TOK 16384   // B*S = 8*2048
#define E_DIM 768
#define FF_DIM 3072
#define Q_N 8

typedef __attribute__((ext_vector_type(8))) short bf16x8;
typedef __attribute__((ext_vector_type(4))) float f32x4;

__device__ inline unsigned short f2bf(float f) {
  union { float f; unsigned u; } v; v.f = f;
  unsigned r = v.u + 0x7fffu + ((v.u >> 16) & 1u);  // round-to-nearest-even
  return (unsigned short)(r >> 16);
}

// ---------------- kernel 0: w2 fp32 -> bf16 ----------------
__global__ __launch_bounds__(256) void cvt_w2(const float* __restrict__ w2,
                                              __hip_bfloat16* __restrict__ w2b) {
  int i = (blockIdx.x * 256 + threadIdx.x) * 4;
  const int n = E_DIM * FF_DIM;
  if (i < n) {
    float4 v = *(const float4*)(w2 + i);
    ushort4 o;
    o.x = f2bf(v.x); o.y = f2bf(v.y); o.z = f2bf(v.z); o.w = f2bf(v.w);
    *(ushort4*)((unsigned short*)w2b + i) = o;
  }
}

// ---------------- kernel 1: h = relu(cos(x[:, :8]+phi) @ w1^T + b1), bf16 ----
__global__ __launch_bounds__(256) void compute_h(const float* __restrict__ x,
                                                 const float* __restrict__ phi,
                                                 const float* __restrict__ w1,
                                                 const float* __restrict__ b1,
                                                 __hip_bfloat16* __restrict__ hout) {
  __shared__ float s_meas[32][8];
  const int t = threadIdx.x;
  const int bm = blockIdx.x / 6;
  const int bf = blockIdx.x % 6;
  const int m0 = bm * 32;
  const int f0 = bf * 512;

  if (t < 64) {
    int m = t >> 1, hh = t & 1;
    float4 v = *(const float4*)(x + (size_t)(m0 + m) * E_DIM + hh * 4);
    float4 p = *(const float4*)(phi + hh * 4);
    s_meas[m][hh * 4 + 0] = __cosf(v.x + p.x);
    s_meas[m][hh * 4 + 1] = __cosf(v.y + p.y);
    s_meas[m][hh * 4 + 2] = __cosf(v.z + p.z);
    s_meas[m][hh * 4 + 3] = __cosf(v.w + p.w);
  }
  __syncthreads();

  const float4* wr = (const float4*)(w1 + (size_t)(f0 + 2 * t) * Q_N);
  float4 a0 = wr[0], a1 = wr[1], b0 = wr[2], b1v = wr[3];
  float wA[8] = {a0.x, a0.y, a0.z, a0.w, a1.x, a1.y, a1.z, a1.w};
  float wB[8] = {b0.x, b0.y, b0.z, b0.w, b1v.x, b1v.y, b1v.z, b1v.w};
  const float biasA = b1[f0 + 2 * t];
  const float biasB = b1[f0 + 2 * t + 1];

  uint32_t* dst32 = (uint32_t*)hout;
  for (int m = 0; m < 32; ++m) {
    float a = biasA, b = biasB;
#pragma unroll
    for (int q = 0; q < 8; ++q) {
      float mv = s_meas[m][q];
      a = fmaf(mv, wA[q], a);
      b = fmaf(mv, wB[q], b);
    }
    a = fmaxf(a, 0.f);
    b = fmaxf(b, 0.f);
    uint32_t pack = (uint32_t)f2bf(a) | ((uint32_t)f2bf(b) << 16);
    dst32[(size_t)(m0 + m) * (FF_DIM / 2) + (f0 / 2) + t] = pack;
  }
}

// ---------------- kernel 2: C[M,N] = h[M,K] @ w2b[N,K]^T + b2 ---------------
// BM=256, BN=192, BK=64 -> grid 64x4 = 256 blocks (100% CU coverage).
// 512 thr (8 waves 2Mx4N), per-wave 128x48, acc[8][3].
// R1: 4-phase schedule per K-tile (T3+T4 port of the 8-phase template):
//   each phase = {ds_read frag subtile || issue stage batch -> raw s_barrier
//   -> lgkmcnt(0)+sched_barrier -> setprio(1) -> 12 MFMA -> setprio(0) ->
//   s_barrier}. All 7 stage loads issued in phases 0-1 (>=3-phase prefetch
//   distance); the single vmcnt(0) sits at phase-3 end where the loads are
//   ~3 phases old, instead of draining freshly-issued loads (old 2-phase).
#define GLDS16(g, l)                                                          \
  __builtin_amdgcn_global_load_lds(                                           \
      (const __attribute__((address_space(1))) void*)(g),                     \
      (__attribute__((address_space(3))) void*)(l), 16, 0, 0)

#define BUF_ELEMS 28672   // (256*64 + 192*64) bf16 elems = 56KB
#define B_OFF 16384       // A region: 256*64 elems

__global__ __launch_bounds__(512, 1) void gemm_bt(const __hip_bfloat16* __restrict__ A,
                                                  const __hip_bfloat16* __restrict__ Bw,
                                                  const float* __restrict__ b2,
                                                  float* __restrict__ C) {
  const int K = FF_DIM;   // 3072
  const int N = E_DIM;    // 768

  __shared__ __align__(16) __hip_bfloat16 lds[2 * BUF_ELEMS];  // 112 KiB

  const int t = threadIdx.x;
  // XCD-aware bijective swizzle: nwg = 256, 256 % 8 == 0
  const int swz = (blockIdx.x & 7) * 32 + (blockIdx.x >> 3);
  const int bm = swz >> 2;        // 0..63
  const int bn = swz & 3;         // 0..3
  const size_t m0 = (size_t)bm * 256;
  const int n0 = bn * 192;

  const int w = t >> 6, l = t & 63;
  const int wr = w >> 2;          // 0..1  (M wave row)
  const int wc = w & 3;           // 0..3  (N wave col)
  const int lr = l & 15;
  const int lk = l >> 4;          // 0..3

  // fragment-read swizzled chunk constants: row&7 == lr&7 for all frag rows
  const int x0 = lk ^ (lr & 7);        // k-half 0 chunk
  const int x1 = x0 ^ 4;               // k-half 1 chunk
  const int baseA = (wr * 128 + lr) * 64;
  const int baseB = B_OFF + (wc * 48 + lr) * 64;
  const int offA0 = baseA + x0 * 8, offA1 = baseA + x1 * 8;
  const int offB0 = baseB + x0 * 8, offB1 = baseB + x1 * 8;

  // staging: span = 64 rows x 128B = 8KB = 512 thr x 16B. dest = t*16B (linear).
  // row-in-span rs = t>>3, phys chunk pc = t&7, logical chunk lc = pc ^ (rs&7).
  const int rs = t >> 3;
  const int lc = (t & 7) ^ (rs & 7);
  const __hip_bfloat16* sA[4];
  const __hip_bfloat16* sB[3];
#pragma unroll
  for (int s = 0; s < 4; ++s) sA[s] = A + (m0 + s * 64 + rs) * (size_t)K + lc * 8;
#pragma unroll
  for (int s = 0; s < 3; ++s) sB[s] = Bw + ((size_t)n0 + s * 64 + rs) * K + lc * 8;

  f32x4 acc[8][3] = {};

#define STAGE_A(K0S, WBUF)                                                    \
  {                                                                           \
    __hip_bfloat16* ld = lds + (WBUF) * BUF_ELEMS + t * 8;                    \
    GLDS16(sA[0] + (K0S), ld);                                                \
    GLDS16(sA[1] + (K0S), ld + 4096);                                         \
    GLDS16(sA[2] + (K0S), ld + 8192);                                         \
    GLDS16(sA[3] + (K0S), ld + 12288);                                        \
  }
#define STAGE_B(K0S, WBUF)                                                    \
  {                                                                           \
    __hip_bfloat16* ld = lds + (WBUF) * BUF_ELEMS + t * 8;                    \
    GLDS16(sB[0] + (K0S), ld + 16384);                                        \
    GLDS16(sB[1] + (K0S), ld + 20480);                                        \
    GLDS16(sB[2] + (K0S), ld + 24576);                                        \
  }

#define PHASE_SYNC_IN()                                                       \
  __builtin_amdgcn_s_barrier();                                               \
  asm volatile("s_waitcnt lgkmcnt(0)" ::: "memory");                          \
  __builtin_amdgcn_sched_barrier(0);                                          \
  __builtin_amdgcn_s_setprio(1)

#define PHASE_SYNC_OUT()                                                      \
  __builtin_amdgcn_s_setprio(0);                                              \
  __builtin_amdgcn_s_barrier()

#define TILE(KT, RBUF, DO_STAGE)                                              \
  {                                                                           \
    const __hip_bfloat16* la = lds + (RBUF) * BUF_ELEMS;                      \
    bf16x8 fa[4], fb0[3], fb1[3];                                             \
    /* ---- phase 0: (mi 0-3) x (ni 0-2), k-half 0; stage A(t+1) ---- */      \
    _Pragma("unroll") for (int mi = 0; mi < 4; ++mi)                          \
        fa[mi] = *(const bf16x8*)(la + offA0 + mi * 1024);                    \
    _Pragma("unroll") for (int ni = 0; ni < 3; ++ni)                          \
        fb0[ni] = *(const bf16x8*)(la + offB0 + ni * 1024);                   \
    if (DO_STAGE) STAGE_A(((KT) + 1) * 64, (RBUF) ^ 1);                       \
    PHASE_SYNC_IN();                                                          \
    _Pragma("unroll") for (int mi = 0; mi < 4; ++mi)                          \
      _Pragma("unroll") for (int ni = 0; ni < 3; ++ni)                        \
        acc[mi][ni] = __builtin_amdgcn_mfma_f32_16x16x32_bf16(                \
            fa[mi], fb0[ni], acc[mi][ni], 0, 0, 0);                           \
    PHASE_SYNC_OUT();                                                         \
    /* ---- phase 1: (mi 4-7) x (ni 0-2), k-half 0; stage B(t+1) ---- */      \
    _Pragma("unroll") for (int mi = 0; mi < 4; ++mi)                          \
        fa[mi] = *(const bf16x8*)(la + offA0 + (mi + 4) * 1024);              \
    if (DO_STAGE) STAGE_B(((KT) + 1) * 64, (RBUF) ^ 1);                       \
    PHASE_SYNC_IN();                                                          \
    _Pragma("unroll") for (int mi = 0; mi < 4; ++mi)                          \
      _Pragma("unroll") for (int ni = 0; ni < 3; ++ni)                        \
        acc[mi + 4][ni] = __builtin_amdgcn_mfma_f32_16x16x32_bf16(            \
            fa[mi], fb0[ni], acc[mi + 4][ni], 0, 0, 0);                       \
    PHASE_SYNC_OUT();                                                         \
    /* ---- phase 2: (mi 0-3) x (ni 0-2), k-half 1 ---- */                    \
    _Pragma("unroll") for (int mi = 0; mi < 4; ++mi)                          \
        fa[mi] = *(const bf16x8*)(la + offA1 + mi * 1024);                    \
    _Pragma("unroll") for (int ni = 0; ni < 3; ++ni)                          \
        fb1[ni] = *(const bf16x8*)(la + offB1 + ni * 1024);                   \
    PHASE_SYNC_IN();                                                          \
    _Pragma("unroll") for (int mi = 0; mi < 4; ++mi)                          \
      _Pragma("unroll") for (int ni = 0; ni < 3; ++ni)                        \
        acc[mi][ni] = __builtin_amdgcn_mfma_f32_16x16x32_bf16(                \
            fa[mi], fb1[ni], acc[mi][ni], 0, 0, 0);                           \
    PHASE_SYNC_OUT();                                                         \
    /* ---- phase 3: (mi 4-7) x (ni 0-2), k-half 1; drain vm at end ---- */   \
    _Pragma("unroll") for (int mi = 0; mi < 4; ++mi)                          \
        fa[mi] = *(const bf16x8*)(la + offA1 + (mi + 4) * 1024);              \
    PHASE_SYNC_IN();                                                          \
    _Pragma("unroll") for (int mi = 0; mi < 4; ++mi)                          \
      _Pragma("unroll") for (int ni = 0; ni < 3; ++ni)                        \
        acc[mi + 4][ni] = __builtin_amdgcn_mfma_f32_16x16x32_bf16(            \
            fa[mi], fb1[ni], acc[mi + 4][ni], 0, 0, 0);                       \
    __builtin_amdgcn_s_setprio(0);                                            \
    asm volatile("s_waitcnt vmcnt(0)" ::: "memory");                          \
    __builtin_amdgcn_s_barrier();                                             \
  }

  // prologue: stage tile 0 into buf 0
  STAGE_A(0, 0);
  STAGE_B(0, 0);
  asm volatile("s_waitcnt vmcnt(0)" ::: "memory");
  __builtin_amdgcn_s_barrier();

  // main: 48 K-tiles of 64, two per iteration (static buffers)
#pragma unroll 1
  for (int tt = 0; tt < 46; tt += 2) {
    TILE(tt + 0, 0, 1);
    TILE(tt + 1, 1, 1);
  }
  TILE(46, 0, 1);
  TILE(47, 1, 0);

#undef TILE
#undef PHASE_SYNC_IN
#undef PHASE_SYNC_OUT
#undef STAGE_A
#undef STAGE_B

  // epilogue: C/D layout col = l&15, row = (l>>4)*4 + r
#pragma unroll
  for (int mi = 0; mi < 8; ++mi) {
    const size_t row = m0 + wr * 128 + mi * 16 + lk * 4;
#pragma unroll
    for (int ni = 0; ni < 3; ++ni) {
      const int col = n0 + wc * 48 + ni * 16 + lr;
      const float bias = b2[col];
#pragma unroll
      for (int rr = 0; rr < 4; ++rr) {
        C[(row + rr) * N + col] = acc[mi][ni][rr] + bias;
      }
    }
  }
}

// ---------------- fallback: correct fp32 path if workspace too small --------
__global__ __launch_bounds__(256) void fallback_fused(const float* __restrict__ x,
                                                      const float* __restrict__ phi,
                                                      const float* __restrict__ w1,
                                                      const float* __restrict__ b1,
                                                      const float* __restrict__ w2,
                                                      const float* __restrict__ b2,
                                                      float* __restrict__ out) {
  __shared__ float s_h[FF_DIM];
  __shared__ float s_meas[Q_N];
  const int t = threadIdx.x;
  const size_t m = blockIdx.x;
  if (t < Q_N) s_meas[t] = __cosf(x[m * E_DIM + t] + phi[t]);
  __syncthreads();
  for (int f = t; f < FF_DIM; f += 256) {
    const float4* wr = (const float4*)(w1 + (size_t)f * Q_N);
    float4 a = wr[0], b = wr[1];
    float acc = b1[f];
    acc = fmaf(s_meas[0], a.x, acc); acc = fmaf(s_meas[1], a.y, acc);
    acc = fmaf(s_meas[2], a.z, acc); acc = fmaf(s_meas[3], a.w, acc);
    acc = fmaf(s_meas[4], b.x, acc); acc = fmaf(s_meas[5], b.y, acc);
    acc = fmaf(s_meas[6], b.z, acc); acc = fmaf(s_meas[7], b.w, acc);
    s_h[f] = fmaxf(acc, 0.f);
  }
  __syncthreads();
  for (int e = t; e < E_DIM; e += 256) {
    const float* w2r = w2 + (size_t)e * FF_DIM;
    float acc = b2[e];
    for (int f = 0; f < FF_DIM; f += 4) {
      float4 wv = *(const float4*)(w2r + f);
      acc = fmaf(s_h[f + 0], wv.x, acc);
      acc = fmaf(s_h[f + 1], wv.y, acc);
      acc = fmaf(s_h[f + 2], wv.z, acc);
      acc = fmaf(s_h[f + 3], wv.w, acc);
    }
    out[m * E_DIM + e] = acc;
  }
}

extern "C" void kernel_launch(void* const* d_in, const int* in_sizes, int n_in,
                              void* d_out, int out_size, void* d_ws, size_t ws_size,
                              hipStream_t stream) {
  const float* x   = (const float*)d_in[0];
  const float* phi = (const float*)d_in[1];
  const float* w1  = (const float*)d_in[2];
  const float* b1  = (const float*)d_in[3];
  const float* w2  = (const float*)d_in[4];
  const float* b2  = (const float*)d_in[5];
  float* out = (float*)d_out;

  const size_t H_BYTES   = (size_t)M_TOK * FF_DIM * 2;   // 100,663,296
  const size_t W2B_BYTES = (size_t)E_DIM * FF_DIM * 2;   // 4,718,592
  const size_t NEED = H_BYTES + W2B_BYTES;

  if (ws_size >= NEED) {
    __hip_bfloat16* h   = (__hip_bfloat16*)d_ws;
    __hip_bfloat16* w2b = (__hip_bfloat16*)((char*)d_ws + H_BYTES);
    cvt_w2<<<(E_DIM * FF_DIM) / (256 * 4), 256, 0, stream>>>(w2, w2b);
    compute_h<<<(M_TOK / 32) * (FF_DIM / 512), 256, 0, stream>>>(x, phi, w1, b1, h);
    // BM=256, BN=192 -> 64*4 = 256 workgroups (matches in-kernel swizzle)
    gemm_bt<<<(M_TOK / 256) * (E_DIM / 192), 512, 0, stream>>>(h, w2b, b2, out);
  } else {
    fallback_fused<<<M_TOK, 256, 0, stream>>>(x, phi, w1, b1, w2, b2, out);
  }
}

// Round 2
// 99.908 us; speedup vs baseline: 1.0157x; 1.0157x over previous
//
#include <hip/hip_runtime.h>
#include <hip/hip_bf16.h>
#include <stdint.h>

// Problem constants
#define M_TOK 16384   // B*S = 8*2048
#define E_DIM 768
#define FF_DIM 3072
#define Q_N 8

typedef __attribute__((ext_vector_type(8))) short bf16x8;
typedef __attribute__((ext_vector_type(4))) float f32x4;

__device__ inline unsigned short f2bf(float f) {
  union { float f; unsigned u; } v; v.f = f;
  unsigned r = v.u + 0x7fffu + ((v.u >> 16) & 1u);  // round-to-nearest-even
  return (unsigned short)(r >> 16);
}

// ---------------- kernel 0: w2 fp32 -> bf16 ----------------
__global__ __launch_bounds__(256) void cvt_w2(const float* __restrict__ w2,
                                              __hip_bfloat16* __restrict__ w2b) {
  int i = (blockIdx.x * 256 + threadIdx.x) * 4;
  const int n = E_DIM * FF_DIM;
  if (i < n) {
    float4 v = *(const float4*)(w2 + i);
    ushort4 o;
    o.x = f2bf(v.x); o.y = f2bf(v.y); o.z = f2bf(v.z); o.w = f2bf(v.w);
    *(ushort4*)((unsigned short*)w2b + i) = o;
  }
}

// ---------------- kernel 1: h = relu(cos(x[:, :8]+phi) @ w1^T + b1), bf16 ----
__global__ __launch_bounds__(256) void compute_h(const float* __restrict__ x,
                                                 const float* __restrict__ phi,
                                                 const float* __restrict__ w1,
                                                 const float* __restrict__ b1,
                                                 __hip_bfloat16* __restrict__ hout) {
  __shared__ float s_meas[32][8];
  const int t = threadIdx.x;
  const int bm = blockIdx.x / 6;
  const int bf = blockIdx.x % 6;
  const int m0 = bm * 32;
  const int f0 = bf * 512;

  if (t < 64) {
    int m = t >> 1, hh = t & 1;
    float4 v = *(const float4*)(x + (size_t)(m0 + m) * E_DIM + hh * 4);
    float4 p = *(const float4*)(phi + hh * 4);
    s_meas[m][hh * 4 + 0] = __cosf(v.x + p.x);
    s_meas[m][hh * 4 + 1] = __cosf(v.y + p.y);
    s_meas[m][hh * 4 + 2] = __cosf(v.z + p.z);
    s_meas[m][hh * 4 + 3] = __cosf(v.w + p.w);
  }
  __syncthreads();

  const float4* wr = (const float4*)(w1 + (size_t)(f0 + 2 * t) * Q_N);
  float4 a0 = wr[0], a1 = wr[1], b0 = wr[2], b1v = wr[3];
  float wA[8] = {a0.x, a0.y, a0.z, a0.w, a1.x, a1.y, a1.z, a1.w};
  float wB[8] = {b0.x, b0.y, b0.z, b0.w, b1v.x, b1v.y, b1v.z, b1v.w};
  const float biasA = b1[f0 + 2 * t];
  const float biasB = b1[f0 + 2 * t + 1];

  uint32_t* dst32 = (uint32_t*)hout;
  for (int m = 0; m < 32; ++m) {
    float a = biasA, b = biasB;
#pragma unroll
    for (int q = 0; q < 8; ++q) {
      float mv = s_meas[m][q];
      a = fmaf(mv, wA[q], a);
      b = fmaf(mv, wB[q], b);
    }
    a = fmaxf(a, 0.f);
    b = fmaxf(b, 0.f);
    uint32_t pack = (uint32_t)f2bf(a) | ((uint32_t)f2bf(b) << 16);
    dst32[(size_t)(m0 + m) * (FF_DIM / 2) + (f0 / 2) + t] = pack;
  }
}

// ---------------- kernel 2: C[M,N] = h[M,K] @ w2b[N,K]^T + b2 ---------------
// BM=256, BN=192, BK=64 -> grid 64x4 = 256 blocks (100% CU coverage).
// 512 thr (8 waves 2Mx4N), per-wave 128x48, acc[8][3].
// R2: R0's proven 2-barrier body + DERIVED COUNTED VMCNT (T4):
//   MFMA half-1 (mi 0-3) needs A-spans {0,2} + all B; half-2 (mi 4-7) needs
//   A-spans {1,3}. Stage split: S_EARLY={B0,B1,B2,A0,A2} at tile start,
//   S_LATE={A1,A3} mid-tile. Steady state: entering a tile, outstanding=2.
//   mid-wait vmcnt(5) retires exactly {A1,A3 of this tile}; end-wait vmcnt(2)
//   retires exactly S_EARLY(next). 5-7 loads stay in flight ACROSS barriers;
//   never drain to 0 in the main loop (last tile: vmcnt(0) mid — with only 2
//   outstanding, vmcnt(5) would be a no-op race).
#define GLDS16(g, l)                                                          \
  __builtin_amdgcn_global_load_lds(                                           \
      (const __attribute__((address_space(1))) void*)(g),                     \
      (__attribute__((address_space(3))) void*)(l), 16, 0, 0)

#define BUF_ELEMS 28672   // (256*64 + 192*64) bf16 elems = 56KB
#define B_OFF 16384       // A region: 256*64 elems

__global__ __launch_bounds__(512, 1) void gemm_bt(const __hip_bfloat16* __restrict__ A,
                                                  const __hip_bfloat16* __restrict__ Bw,
                                                  const float* __restrict__ b2,
                                                  float* __restrict__ C) {
  const int K = FF_DIM;   // 3072
  const int N = E_DIM;    // 768

  __shared__ __align__(16) __hip_bfloat16 lds[2 * BUF_ELEMS];  // 112 KiB

  const int t = threadIdx.x;
  // XCD-aware bijective swizzle: nwg = 256, 256 % 8 == 0
  const int swz = (blockIdx.x & 7) * 32 + (blockIdx.x >> 3);
  const int bm = swz >> 2;        // 0..63
  const int bn = swz & 3;         // 0..3
  const size_t m0 = (size_t)bm * 256;
  const int n0 = bn * 192;

  const int w = t >> 6, l = t & 63;
  const int wr = w >> 2;          // 0..1  (M wave row)
  const int wc = w & 3;           // 0..3  (N wave col)
  const int lr = l & 15;
  const int lk = l >> 4;          // 0..3

  // fragment-read swizzled chunk constants: row&7 == lr&7 for all frag rows
  const int x0 = lk ^ (lr & 7);        // k-half 0 chunk
  const int x1 = x0 ^ 4;               // k-half 1 chunk
  const int baseA = (wr * 128 + lr) * 64;
  const int baseB = B_OFF + (wc * 48 + lr) * 64;
  const int offA0 = baseA + x0 * 8, offA1 = baseA + x1 * 8;
  const int offB0 = baseB + x0 * 8, offB1 = baseB + x1 * 8;

  // staging: span = 64 rows x 128B = 8KB = 512 thr x 16B. dest = t*16B (linear).
  // row-in-span rs = t>>3, phys chunk pc = t&7, logical chunk lc = pc ^ (rs&7).
  const int rs = t >> 3;
  const int lc = (t & 7) ^ (rs & 7);
  const __hip_bfloat16* sA[4];
  const __hip_bfloat16* sB[3];
#pragma unroll
  for (int s = 0; s < 4; ++s) sA[s] = A + (m0 + s * 64 + rs) * (size_t)K + lc * 8;
#pragma unroll
  for (int s = 0; s < 3; ++s) sB[s] = Bw + ((size_t)n0 + s * 64 + rs) * K + lc * 8;

  f32x4 acc[8][3] = {};

  // S_EARLY: everything MFMA half-1 needs next tile (B all, A spans 0 and 2)
#define S_EARLY(K0S, WBUF)                                                    \
  {                                                                           \
    __hip_bfloat16* ld = lds + (WBUF) * BUF_ELEMS + t * 8;                    \
    GLDS16(sB[0] + (K0S), ld + 16384);                                        \
    GLDS16(sB[1] + (K0S), ld + 20480);                                        \
    GLDS16(sB[2] + (K0S), ld + 24576);                                        \
    GLDS16(sA[0] + (K0S), ld);                                                \
    GLDS16(sA[2] + (K0S), ld + 8192);                                         \
  }
  // S_LATE: A spans 1 and 3 (only needed by MFMA half-2 next tile)
#define S_LATE(K0S, WBUF)                                                     \
  {                                                                           \
    __hip_bfloat16* ld = lds + (WBUF) * BUF_ELEMS + t * 8;                    \
    GLDS16(sA[1] + (K0S), ld + 4096);                                         \
    GLDS16(sA[3] + (K0S), ld + 12288);                                        \
  }

#define TILE(KT, RBUF, DO_STAGE)                                              \
  {                                                                           \
    const __hip_bfloat16* la = lds + (RBUF) * BUF_ELEMS;                      \
    if (DO_STAGE) S_EARLY(((KT) + 1) * 64, (RBUF) ^ 1);                       \
    bf16x8 af0[4], af1[4], bfx0[3], bfx1[3];                                  \
    _Pragma("unroll") for (int mi = 0; mi < 4; ++mi) {                        \
      af0[mi] = *(const bf16x8*)(la + offA0 + mi * 1024);                     \
      af1[mi] = *(const bf16x8*)(la + offA1 + mi * 1024);                     \
    }                                                                         \
    _Pragma("unroll") for (int ni = 0; ni < 3; ++ni) {                        \
      bfx0[ni] = *(const bf16x8*)(la + offB0 + ni * 1024);                    \
      bfx1[ni] = *(const bf16x8*)(la + offB1 + ni * 1024);                    \
    }                                                                         \
    __builtin_amdgcn_s_setprio(1);                                            \
    _Pragma("unroll") for (int mi = 0; mi < 4; ++mi)                          \
      _Pragma("unroll") for (int ni = 0; ni < 3; ++ni)                        \
        acc[mi][ni] = __builtin_amdgcn_mfma_f32_16x16x32_bf16(                \
            af0[mi], bfx0[ni], acc[mi][ni], 0, 0, 0);                         \
    _Pragma("unroll") for (int mi = 0; mi < 4; ++mi)                          \
      _Pragma("unroll") for (int ni = 0; ni < 3; ++ni)                        \
        acc[mi][ni] = __builtin_amdgcn_mfma_f32_16x16x32_bf16(                \
            af1[mi], bfx1[ni], acc[mi][ni], 0, 0, 0);                         \
    __builtin_amdgcn_s_setprio(0);                                            \
    if (DO_STAGE) {                                                           \
      asm volatile("s_waitcnt vmcnt(5)" ::: "memory");  /* retire A1,A3(t) */ \
    } else {                                                                  \
      asm volatile("s_waitcnt vmcnt(0)" ::: "memory");                        \
    }                                                                         \
    __builtin_amdgcn_s_barrier();                                             \
    bf16x8 ag0[4], ag1[4];                                                    \
    _Pragma("unroll") for (int mi = 0; mi < 4; ++mi) {                        \
      ag0[mi] = *(const bf16x8*)(la + offA0 + (mi + 4) * 1024);               \
      ag1[mi] = *(const bf16x8*)(la + offA1 + (mi + 4) * 1024);               \
    }                                                                         \
    if (DO_STAGE) S_LATE(((KT) + 1) * 64, (RBUF) ^ 1);                        \
    __builtin_amdgcn_s_setprio(1);                                            \
    _Pragma("unroll") for (int mi = 0; mi < 4; ++mi)                          \
      _Pragma("unroll") for (int ni = 0; ni < 3; ++ni)                        \
        acc[mi + 4][ni] = __builtin_amdgcn_mfma_f32_16x16x32_bf16(            \
            ag0[mi], bfx0[ni], acc[mi + 4][ni], 0, 0, 0);                     \
    _Pragma("unroll") for (int mi = 0; mi < 4; ++mi)                          \
      _Pragma("unroll") for (int ni = 0; ni < 3; ++ni)                        \
        acc[mi + 4][ni] = __builtin_amdgcn_mfma_f32_16x16x32_bf16(            \
            ag1[mi], bfx1[ni], acc[mi + 4][ni], 0, 0, 0);                     \
    __builtin_amdgcn_s_setprio(0);                                            \
    if (DO_STAGE) {                                                           \
      asm volatile("s_waitcnt vmcnt(2)" ::: "memory"); /* retire S_EARLY(t+1) */ \
      __builtin_amdgcn_s_barrier();                                           \
    }                                                                         \
  }

  // prologue: stage tile 0 into buf 0; leave A1,A3 in flight (invariant = 2)
  S_EARLY(0, 0);
  S_LATE(0, 0);
  asm volatile("s_waitcnt vmcnt(2)" ::: "memory");
  __builtin_amdgcn_s_barrier();

  // main: 48 K-tiles of 64, two per iteration (static buffers)
#pragma unroll 1
  for (int tt = 0; tt < 46; tt += 2) {
    TILE(tt + 0, 0, 1);
    TILE(tt + 1, 1, 1);
  }
  TILE(46, 0, 1);
  TILE(47, 1, 0);

#undef TILE
#undef S_EARLY
#undef S_LATE

  // epilogue: C/D layout col = l&15, row = (l>>4)*4 + r
#pragma unroll
  for (int mi = 0; mi < 8; ++mi) {
    const size_t row = m0 + wr * 128 + mi * 16 + lk * 4;
#pragma unroll
    for (int ni = 0; ni < 3; ++ni) {
      const int col = n0 + wc * 48 + ni * 16 + lr;
      const float bias = b2[col];
#pragma unroll
      for (int rr = 0; rr < 4; ++rr) {
        C[(row + rr) * N + col] = acc[mi][ni][rr] + bias;
      }
    }
  }
}

// ---------------- fallback: correct fp32 path if workspace too small --------
__global__ __launch_bounds__(256) void fallback_fused(const float* __restrict__ x,
                                                      const float* __restrict__ phi,
                                                      const float* __restrict__ w1,
                                                      const float* __restrict__ b1,
                                                      const float* __restrict__ w2,
                                                      const float* __restrict__ b2,
                                                      float* __restrict__ out) {
  __shared__ float s_h[FF_DIM];
  __shared__ float s_meas[Q_N];
  const int t = threadIdx.x;
  const size_t m = blockIdx.x;
  if (t < Q_N) s_meas[t] = __cosf(x[m * E_DIM + t] + phi[t]);
  __syncthreads();
  for (int f = t; f < FF_DIM; f += 256) {
    const float4* wr = (const float4*)(w1 + (size_t)f * Q_N);
    float4 a = wr[0], b = wr[1];
    float acc = b1[f];
    acc = fmaf(s_meas[0], a.x, acc); acc = fmaf(s_meas[1], a.y, acc);
    acc = fmaf(s_meas[2], a.z, acc); acc = fmaf(s_meas[3], a.w, acc);
    acc = fmaf(s_meas[4], b.x, acc); acc = fmaf(s_meas[5], b.y, acc);
    acc = fmaf(s_meas[6], b.z, acc); acc = fmaf(s_meas[7], b.w, acc);
    s_h[f] = fmaxf(acc, 0.f);
  }
  __syncthreads();
  for (int e = t; e < E_DIM; e += 256) {
    const float* w2r = w2 + (size_t)e * FF_DIM;
    float acc = b2[e];
    for (int f = 0; f < FF_DIM; f += 4) {
      float4 wv = *(const float4*)(w2r + f);
      acc = fmaf(s_h[f + 0], wv.x, acc);
      acc = fmaf(s_h[f + 1], wv.y, acc);
      acc = fmaf(s_h[f + 2], wv.z, acc);
      acc = fmaf(s_h[f + 3], wv.w, acc);
    }
    out[m * E_DIM + e] = acc;
  }
}

extern "C" void kernel_launch(void* const* d_in, const int* in_sizes, int n_in,
                              void* d_out, int out_size, void* d_ws, size_t ws_size,
                              hipStream_t stream) {
  const float* x   = (const float*)d_in[0];
  const float* phi = (const float*)d_in[1];
  const float* w1  = (const float*)d_in[2];
  const float* b1  = (const float*)d_in[3];
  const float* w2  = (const float*)d_in[4];
  const float* b2  = (const float*)d_in[5];
  float* out = (float*)d_out;

  const size_t H_BYTES   = (size_t)M_TOK * FF_DIM * 2;   // 100,663,296
  const size_t W2B_BYTES = (size_t)E_DIM * FF_DIM * 2;   // 4,718,592
  const size_t NEED = H_BYTES + W2B_BYTES;

  if (ws_size >= NEED) {
    __hip_bfloat16* h   = (__hip_bfloat16*)d_ws;
    __hip_bfloat16* w2b = (__hip_bfloat16*)((char*)d_ws + H_BYTES);
    cvt_w2<<<(E_DIM * FF_DIM) / (256 * 4), 256, 0, stream>>>(w2, w2b);
    compute_h<<<(M_TOK / 32) * (FF_DIM / 512), 256, 0, stream>>>(x, phi, w1, b1, h);
    // BM=256, BN=192 -> 64*4 = 256 workgroups (matches in-kernel swizzle)
    gemm_bt<<<(M_TOK / 256) * (E_DIM / 192), 512, 0, stream>>>(h, w2b, b2, out);
  } else {
    fallback_fused<<<M_TOK, 256, 0, stream>>>(x, phi, w1, b1, w2, b2, out);
  }
}